// Round 12
// baseline (544.200 us; speedup 1.0000x reference)
//
#include <hip/hip_runtime.h>
#include <hip/hip_bf16.h>

#define B_   4
#define T_   4096
#define DM   1024
#define H_   8
#define DH   128
#define BHN  32
#define NH   4
#define NB   64
#define NT   16384
#define NC   256
#define SCALE_ 0.08838834764831845f
#define SELF_VAL -50000.0f
#define FLAG_CAP 262144
#define GAP_THR 2.5e-3f

typedef unsigned short u16;
typedef __attribute__((ext_vector_type(8))) short short8;
typedef __attribute__((ext_vector_type(8))) unsigned short us8;
typedef __attribute__((ext_vector_type(4))) float f32x4;

__device__ __forceinline__ float bf2f(u16 x) {
  union { unsigned u; float f; } c; c.u = ((unsigned)x) << 16; return c.f;
}
__device__ __forceinline__ u16 f2bf(float f) {
  union { float f; unsigned u; } c; c.f = f;
  unsigned r = (c.u + 0x7FFFu + ((c.u >> 16) & 1u)) >> 16;
  return (u16)r;
}
// async global->LDS, 16B per lane; LDS dest = wave-uniform base + lane*16
__device__ __forceinline__ void gload16(const void* g, void* l) {
  __builtin_amdgcn_global_load_lds(
      (const __attribute__((address_space(1))) void*)g,
      (__attribute__((address_space(3))) void*)l, 16, 0, 0);
}

// ---------------------------------------------------------------------------
// P1: split i -> i_hi (bf16) and i_lo (bf16 of residual)
// ---------------------------------------------------------------------------
__global__ __launch_bounds__(256) void k_isplit(
    const float* __restrict__ I, u16* __restrict__ ih, u16* __restrict__ il) {
  size_t idx = ((size_t)blockIdx.x * 256 + threadIdx.x) * 8;
  us8 vh, vl;
  #pragma unroll
  for (int e = 0; e < 8; ++e) {
    float x = I[idx + e];
    u16 h = f2bf(x);
    vh[e] = h;
    vl[e] = f2bf(x - bf2f(h));
  }
  *(us8*)(ih + idx) = vh;
  *(us8*)(il + idx) = vl;
}

// ---------------------------------------------------------------------------
// P2: WR[h][k][hr] = sum_d Wqk[k][h*128+d] * R[d][hr]  (f64, for k_fb only)
// ---------------------------------------------------------------------------
__global__ __launch_bounds__(256) void k_wr(
    const float* __restrict__ Wqk, const float* __restrict__ R, double* __restrict__ WR) {
  __shared__ float lR[128][128];
  int tid = threadIdx.x;
  int k0 = blockIdx.x * 64, h = blockIdx.y;
  #pragma unroll
  for (int q = 0; q < 64; ++q)
    ((float*)lR)[q * 256 + tid] = R[q * 256 + tid];
  __syncthreads();
  int k = k0 + (tid >> 2);
  int hr0 = (tid & 3) * 32;
  double acc[32];
  #pragma unroll
  for (int j = 0; j < 32; ++j) acc[j] = 0.0;
  for (int d = 0; d < 128; ++d) {
    double w = (double)Wqk[(size_t)k * DM + h * DH + d];
    #pragma unroll
    for (int j = 0; j < 32; ++j)
      acc[j] = fma(w, (double)lR[d][hr0 + j], acc[j]);
  }
  double* o = WR + ((size_t)h * 1024 + k) * 128 + hr0;
  #pragma unroll
  for (int j = 0; j < 32; ++j) o[j] = acc[j];
}

// ---------------------------------------------------------------------------
// P3: transpose+split weights (also zeroes flagc): Wqkvt contiguous [2048][1024],
// Wot bf16 [n][k], WR2t [n][2048]={hi,lo}
// ---------------------------------------------------------------------------
__global__ __launch_bounds__(256) void k_wsplit(
    const float* __restrict__ Wqk, const float* __restrict__ Wv,
    const float* __restrict__ Wo, const double* __restrict__ WR,
    u16* __restrict__ Wqkvt, u16* __restrict__ Wot, u16* __restrict__ WR2t,
    unsigned* __restrict__ flagc) {
  if (blockIdx.x == 0 && threadIdx.x == 0) *flagc = 0;
  int tid = blockIdx.x * 256 + threadIdx.x;   // 131072
  int k = tid >> 7, n8 = (tid & 127) << 3;
  #pragma unroll
  for (int j = 0; j < 8; ++j) {
    int n = n8 + j;
    Wqkvt[(size_t)n * 1024 + k]          = f2bf(Wqk[(size_t)k * 1024 + n]);
    Wqkvt[(size_t)(1024 + n) * 1024 + k] = f2bf(Wv [(size_t)k * 1024 + n]);
    Wot  [(size_t)n * 1024 + k]          = f2bf(Wo [(size_t)k * 1024 + n]);
    double w = WR[((size_t)(n >> 7) * 1024 + k) * 128 + (n & 127)];
    u16 wh = f2bf((float)w);
    u16 wl = f2bf((float)(w - (double)bf2f(wh)));
    WR2t[(size_t)n * 2048 + k] = wh;
    WR2t[(size_t)n * 2048 + 1024 + k] = wl;
  }
}

// ---------------------------------------------------------------------------
// P5: recipn[bt][h] = 1 / max(||qk[bt][h*128..]||, 1e-6). 2 bt-rows per block.
// ---------------------------------------------------------------------------
__global__ __launch_bounds__(256) void k_norm(
    const u16* __restrict__ qk, float* __restrict__ rn) {
  int tid = threadIdx.x;
  int g = tid >> 4, l = tid & 15;
  int row = blockIdx.x * 2 + (g >> 3), head = g & 7;
  us8 x = *(const us8*)(qk + (size_t)row * DM + head * DH + l * 8);
  float ss = 0.f;
  #pragma unroll
  for (int e = 0; e < 8; ++e) {
    float f = bf2f((u16)x[e]);
    ss += f * f;
  }
  #pragma unroll
  for (int m = 1; m <= 8; m <<= 1) ss += __shfl_xor(ss, m, 64);
  if (l == 0) rn[(size_t)row * 8 + head] = 1.f / fmaxf(sqrtf(ss), 1e-6f);
}

// ---------------------------------------------------------------------------
// K-GEMM: C[M x N] = A * Bt^T, bf16 MFMA, 128x128 tile, gload_lds staging with
// 16B-chunk XOR swizzle (both-sides involution, rule #21).
// EPI 0: bf16 store, N=2048 split across outb (cols<1024) / outb2.
// EPI 1: f32 + bias (N=1024).
// EPI 2: rot GEMM as 3 segments [A*Bhi, A*Blo, A2*Bhi]; argmax epilogue.
// ---------------------------------------------------------------------------
template <int EPI>
__global__ __launch_bounds__(256) void k_gemm(
    const u16* __restrict__ A, const u16* __restrict__ A2,
    const u16* __restrict__ Bt,
    u16* __restrict__ outb, u16* __restrict__ outb2,
    float* __restrict__ outf, const float* __restrict__ bias,
    int* __restrict__ buckets, unsigned* __restrict__ flagc, int* __restrict__ flags) {
  __shared__ char smem[34816];                       // A[0,16K) B[16K,32K); sC 33792B
  u16 (*smA)[64] = (u16 (*)[64])smem;
  u16 (*smB)[64] = (u16 (*)[64])(smem + 16384);
  int tid = threadIdx.x;
  int m0 = blockIdx.x * 128, n0 = blockIdx.y * 128;
  int w = tid >> 6, lane = tid & 63;
  int wr = w >> 1, wc = w & 1;
  int arow = lane & 15, kg = lane >> 4;
  const int ldb = (EPI == 2) ? 2048 : 1024;
  int lrow = lane >> 3;                              // row within 8-row group = row&7
  int gch = (lane & 7) ^ lrow;                       // swizzled source 16B chunk

  f32x4 acc[4][4];
  #pragma unroll
  for (int m = 0; m < 4; ++m)
    #pragma unroll
    for (int n = 0; n < 4; ++n) acc[m][n] = (f32x4){0.f, 0.f, 0.f, 0.f};

  int axor = (arow & 7) << 3;                        // chunk-XOR premultiplied by 8

  auto run_seg = [&](const u16* Ab, const u16* Bb) {
    for (int kk = 0; kk < 1024; kk += 64) {
      __syncthreads();                               // prior MFMA reads done
      #pragma unroll
      for (int q = 0; q < 4; ++q) {
        int row = q * 32 + w * 8 + lrow;
        gload16(Ab + (size_t)(m0 + row) * 1024 + kk + gch * 8,
                smem + (q * 4096 + w * 1024));
        gload16(Bb + (size_t)(n0 + row) * ldb + kk + gch * 8,
                smem + 16384 + (q * 4096 + w * 1024));
      }
      __syncthreads();                               // staging drained
      #pragma unroll
      for (int ks = 0; ks < 2; ++ks) {
        short8 af[4], bf[4];
        #pragma unroll
        for (int m = 0; m < 4; ++m)
          af[m] = *(const short8*)(&smA[wr * 64 + m * 16 + arow][((ks * 4 + kg) << 3) ^ axor]);
        #pragma unroll
        for (int n = 0; n < 4; ++n)
          bf[n] = *(const short8*)(&smB[wc * 64 + n * 16 + arow][((ks * 4 + kg) << 3) ^ axor]);
        #pragma unroll
        for (int m = 0; m < 4; ++m)
          #pragma unroll
          for (int n = 0; n < 4; ++n)
            acc[m][n] = __builtin_amdgcn_mfma_f32_16x16x32_bf16(af[m], bf[n], acc[m][n], 0, 0, 0);
      }
    }
  };

  if constexpr (EPI == 2) {
    run_seg(A, Bt);            // i_hi * W_hi
    run_seg(A, Bt + 1024);     // i_hi * W_lo
    run_seg(A2, Bt);           // i_lo * W_hi
  } else {
    run_seg(A, Bt);
  }

  if constexpr (EPI == 0) {
    u16* dst = (n0 < 1024) ? outb : outb2;
    int nc0 = (n0 < 1024) ? n0 : (n0 - 1024);
    #pragma unroll
    for (int m = 0; m < 4; ++m)
      #pragma unroll
      for (int n = 0; n < 4; ++n)
        #pragma unroll
        for (int r = 0; r < 4; ++r) {
          int orow = wr * 64 + m * 16 + kg * 4 + r;
          int ocol = wc * 64 + n * 16 + arow;
          dst[(size_t)(m0 + orow) * 1024 + nc0 + ocol] = f2bf(acc[m][n][r]);
        }
  } else if constexpr (EPI == 1) {
    #pragma unroll
    for (int m = 0; m < 4; ++m)
      #pragma unroll
      for (int n = 0; n < 4; ++n)
        #pragma unroll
        for (int r = 0; r < 4; ++r) {
          int orow = wr * 64 + m * 16 + kg * 4 + r;
          int ocol = wc * 64 + n * 16 + arow;
          outf[(size_t)(m0 + orow) * 1024 + n0 + ocol] = acc[m][n][r] + bias[n0 + ocol];
        }
  } else {
    // rot epilogue: this block's N-tile is exactly head h = blockIdx.y.
    float (*sC)[132] = (float (*)[132])smem;         // 64*132*4 = 33792 B
    #pragma unroll
    for (int pass = 0; pass < 2; ++pass) {
      __syncthreads();   // previous phase done with smem
      if (wr == pass) {
        #pragma unroll
        for (int m = 0; m < 4; ++m)
          #pragma unroll
          for (int n = 0; n < 4; ++n)
            #pragma unroll
            for (int r = 0; r < 4; ++r)
              sC[m * 16 + kg * 4 + r][wc * 64 + n * 16 + arow] = acc[m][n][r];
      }
      __syncthreads();
      int tok = tid >> 2, hash = tid & 3;
      const float* rw = &sC[tok][hash * 32];
      float m1 = -3.4e38f, m2 = -3.4e38f; int bi = 0;
      #pragma unroll
      for (int j = 0; j < 32; ++j) {
        float vv = rw[j];
        if (vv > m1) { m2 = m1; m1 = vv; bi = j; }
        else if (vv > m2) m2 = vv;
      }
      #pragma unroll
      for (int j = 0; j < 32; ++j) {
        float vv = -rw[j];
        if (vv > m1) { m2 = m1; m1 = vv; bi = 32 + j; }
        else if (vv > m2) m2 = vv;
      }
      int bt = m0 + pass * 64 + tok;
      int b = bt >> 12, t = bt & 4095;
      buckets[((size_t)(b * 8 + blockIdx.y) * 4 + hash) * T_ + t] = bi;
      if (m1 - m2 < GAP_THR) {
        unsigned pos = atomicAdd(flagc, 1u);
        if (pos < FLAG_CAP) flags[pos] = (bt << 5) | ((int)blockIdx.y << 2) | hash;
      }
    }
  }
}

// ---------------------------------------------------------------------------
// f64 fallback for near-tie argmaxes: recompute 32 rot dots exactly.
// ---------------------------------------------------------------------------
__global__ __launch_bounds__(64) void k_fb(
    const float* __restrict__ I, const double* __restrict__ WR,
    const unsigned* __restrict__ flagc, const int* __restrict__ flags,
    int* __restrict__ buckets) {
  unsigned n = *flagc; if (n > FLAG_CAP) n = FLAG_CAP;
  int lane = threadIdx.x;
  for (unsigned it = blockIdx.x; it < n; it += gridDim.x) {
    int f = flags[it];
    int bt = f >> 5, h = (f >> 2) & 7, hash = f & 3;
    int j = lane & 31, half = lane >> 5;
    const float* ip = I + (size_t)bt * 1024 + half * 512;
    const double* wp = WR + ((size_t)h * 1024 + half * 512) * 128 + hash * 32 + j;
    double acc = 0.0;
    for (int k = 0; k < 512; ++k)
      acc = fma((double)ip[k], wp[(size_t)k * 128], acc);
    acc += __shfl_down(acc, 32, 64);
    double bv = acc; int bi = j;
    double vneg = -acc;
    if (vneg > bv) { bv = vneg; bi = 32 + j; }
    #pragma unroll
    for (int m = 1; m < 32; m <<= 1) {
      double ov = __shfl_xor(bv, m, 64);
      int oi = __shfl_xor(bi, m, 64);
      if (ov > bv || (ov == bv && oi < bi)) { bv = ov; bi = oi; }
    }
    if (lane == 0) {
      int b = bt >> 12, t = bt & 4095;
      buckets[((size_t)(b * 8 + h) * 4 + hash) * T_ + t] = bi;
    }
  }
}

// ---------------------------------------------------------------------------
// K3: stable counting sort (st only)
// ---------------------------------------------------------------------------
__global__ __launch_bounds__(64) void k_sort(
    const int* __restrict__ buckets, int* __restrict__ st) {
  __shared__ int hist[64][65];
  __shared__ int base[64];
  int bh = blockIdx.x, r = blockIdx.y;
  int m = threadIdx.x;
  #pragma unroll
  for (int b = 0; b < 64; ++b) hist[b][m] = 0;
  __syncthreads();
  const int* bk = buckets + ((size_t)bh * NH + r) * T_;
  for (int q = 0; q < 64; ++q) hist[bk[m * 64 + q]][m]++;
  __syncthreads();
  {
    int run = 0;
    for (int c = 0; c < 64; ++c) { int x = hist[m][c]; hist[m][c] = run; run += x; }
    base[m] = run;
  }
  __syncthreads();
  if (m == 0) {
    int s = 0;
    for (int b = 0; b < 64; ++b) { int x = base[b]; base[b] = s; s += x; }
  }
  __syncthreads();
  int* stb = st + (size_t)bh * NT + (size_t)r * T_;
  for (int q = 0; q < 64; ++q) {
    int t = m * 64 + q;
    int b = bk[t];
    int pos = base[b] + hist[b][m]++;
    stb[pos] = t;
  }
}

// ---------------------------------------------------------------------------
// k_attn v4: precomputed recipn (pure-copy q staging); V^T staging issued
// before softmax finish (latency hidden under exp chain); 4 barriers.
// ---------------------------------------------------------------------------
__global__ __launch_bounds__(256) void k_attn(
    const u16* __restrict__ qk, const u16* __restrict__ V, const int* __restrict__ st,
    const float* __restrict__ rn, u16* __restrict__ o_u, float* __restrict__ slog_u) {
  __shared__ u16 kbuf[128][136];   // q rows [key][d]; later V^T [d][key]
  __shared__ u16 pbuf[64][136];    // probs bf16 [q][key]
  __shared__ int tks[128];
  float* recipn = (float*)&pbuf[0][0];   // 512 B, dead before prob writes
  int tid = threadIdx.x;
  int bh = blockIdx.x, chunk = blockIdx.y;
  int round = chunk >> 6;
  int bb_ = bh >> 3, hh_ = bh & 7;
  const int* stb = st + (size_t)bh * NT;
  if (tid < 128) {
    int j = tid;
    int p = (j < 64) ? (chunk * 64 + j)
                     : (((chunk + NC - 1) % NC) * 64 + (j - 64));
    tks[j] = stb[p];
  }
  __syncthreads();
  {
    int j = tid & 127, half = tid >> 7;
    const us8* rp = (const us8*)(qk + ((size_t)(bb_ * T_ + tks[j])) * DM + hh_ * DH + half * 64);
    us8* dp = (us8*)(&kbuf[j][half * 64]);
    #pragma unroll
    for (int c = 0; c < 8; ++c) dp[c] = rp[c];
  }
  if (tid < 128) recipn[tid] = rn[(size_t)(bb_ * T_ + tks[tid]) * 8 + hh_];
  __syncthreads();

  int w = tid >> 6, lane = tid & 63;
  int arow = lane & 15, kgrp = lane >> 4;

  f32x4 acc[8];
  #pragma unroll
  for (int n = 0; n < 8; ++n) acc[n] = (f32x4){0.f, 0.f, 0.f, 0.f};
  __builtin_amdgcn_s_setprio(1);
  #pragma unroll
  for (int kk = 0; kk < 4; ++kk) {
    short8 a = *(const short8*)(&kbuf[w * 16 + arow][kk * 32 + kgrp * 8]);
    #pragma unroll
    for (int n = 0; n < 8; ++n) {
      short8 bb = *(const short8*)(&kbuf[n * 16 + arow][kk * 32 + kgrp * 8]);
      acc[n] = __builtin_amdgcn_mfma_f32_16x16x32_bf16(a, bb, acc[n], 0, 0, 0);
    }
  }
  __builtin_amdgcn_s_setprio(0);

  int ti[4];
  #pragma unroll
  for (int r = 0; r < 4; ++r) ti[r] = tks[w * 16 + kgrp * 4 + r];
  float vals[8][4];
  float rmax[4] = {-3.0e38f, -3.0e38f, -3.0e38f, -3.0e38f};
  #pragma unroll
  for (int n = 0; n < 8; ++n) {
    int j = n * 16 + arow;
    float rc = recipn[j] * SCALE_;
    int tj = tks[j];
    #pragma unroll
    for (int r = 0; r < 4; ++r) {
      float d = acc[n][r] * rc;
      if (ti[r] == tj) d = SELF_VAL;
      vals[n][r] = d;
      rmax[r] = fmaxf(rmax[r], d);
    }
  }
  __syncthreads();   // all QK^T kbuf reads + recipn reads complete

  // V^T staging issued FIRST: global-load latency hides under softmax VALU
  {
    int j = tid & 127, half = tid >> 7;
    const us8* rp = (const us8*)(V + ((size_t)(bb_ * T_ + tks[j])) * DM + hh_ * DH + half * 64);
    #pragma unroll
    for (int c = 0; c < 8; ++c) {
      us8 x = rp[c];
      int d = half * 64 + c * 8;
      #pragma unroll
      for (int e = 0; e < 8; ++e) kbuf[d + e][j] = (u16)x[e];
    }
  }

  #pragma unroll
  for (int m = 1; m <= 8; m <<= 1) {
    #pragma unroll
    for (int r = 0; r < 4; ++r) rmax[r] = fmaxf(rmax[r], __shfl_xor(rmax[r], m, 64));
  }
  float rsum[4] = {0.f, 0.f, 0.f, 0.f};
  #pragma unroll
  for (int n = 0; n < 8; ++n) {
    #pragma unroll
    for (int r = 0; r < 4; ++r) {
      float e = __expf(vals[n][r] - rmax[r]);
      vals[n][r] = e;
      rsum[r] += e;
    }
  }
  #pragma unroll
  for (int m = 1; m <= 8; m <<= 1) {
    #pragma unroll
    for (int r = 0; r < 4; ++r) rsum[r] += __shfl_xor(rsum[r], m, 64);
  }
  float rinv[4], lse[4];
  #pragma unroll
  for (int r = 0; r < 4; ++r) {
    rinv[r] = 1.f / rsum[r];
    lse[r] = rmax[r] + __logf(rsum[r]);
  }
  if (arow == 0) {
    #pragma unroll
    for (int r = 0; r < 4; ++r)
      slog_u[((size_t)(bh * NH + round)) * T_ + ti[r]] = lse[r];
  }
  #pragma unroll
  for (int n = 0; n < 8; ++n) {
    #pragma unroll
    for (int r = 0; r < 4; ++r)
      pbuf[w * 16 + kgrp * 4 + r][n * 16 + arow] = f2bf(vals[n][r] * rinv[r]);
  }
  __syncthreads();   // probs + V^T both complete

  f32x4 acc2[8];
  #pragma unroll
  for (int n = 0; n < 8; ++n) acc2[n] = (f32x4){0.f, 0.f, 0.f, 0.f};
  __builtin_amdgcn_s_setprio(1);
  #pragma unroll
  for (int kk = 0; kk < 4; ++kk) {
    short8 a = *(const short8*)(&pbuf[w * 16 + arow][kk * 32 + kgrp * 8]);
    #pragma unroll
    for (int n = 0; n < 8; ++n) {
      short8 bb = *(const short8*)(&kbuf[n * 16 + arow][kk * 32 + kgrp * 8]);
      acc2[n] = __builtin_amdgcn_mfma_f32_16x16x32_bf16(a, bb, acc2[n], 0, 0, 0);
    }
  }
  __builtin_amdgcn_s_setprio(0);
  u16* ob = o_u + ((size_t)(bh * NH + round)) * T_ * DH;
  #pragma unroll
  for (int n = 0; n < 8; ++n) {
    #pragma unroll
    for (int r = 0; r < 4; ++r)
      ob[(size_t)ti[r] * DH + n * 16 + arow] = f2bf(acc2[n][r]);
  }
}

// ---------------------------------------------------------------------------
// k_comb v2: unsorted inputs -> fully coalesced. 16 tokens per block.
// ---------------------------------------------------------------------------
__global__ __launch_bounds__(256) void k_comb(
    const u16* __restrict__ o_u, const float* __restrict__ slog_u,
    u16* __restrict__ attn) {
  int tid = threadIdx.x;
  int bh = blockIdx.y;
  int t0 = blockIdx.x * 16;
  int dd = tid & 127;
  int b = bh >> 3, h = bh & 7;
  #pragma unroll
  for (int i = 0; i < 8; ++i) {
    int t = t0 + (tid >> 7) + i * 2;
    float l[4];
    #pragma unroll
    for (int r = 0; r < 4; ++r)
      l[r] = slog_u[((size_t)(bh * NH + r)) * T_ + t];
    float m = fmaxf(fmaxf(l[0], l[1]), fmaxf(l[2], l[3]));
    float wv[4]; float wsum = 0.f;
    #pragma unroll
    for (int r = 0; r < 4; ++r) { wv[r] = __expf(l[r] - m); wsum += wv[r]; }
    float rs = 1.f / wsum;
    float o = 0.f;
    #pragma unroll
    for (int r = 0; r < 4; ++r)
      o += wv[r] * bf2f(o_u[(((size_t)(bh * NH + r)) * T_ + t) * DH + dd]);
    o *= rs;
    attn[((size_t)(b * T_ + t)) * DM + h * DH + dd] = f2bf(o);
  }
}

__global__ __launch_bounds__(256) void k_ln(
    const float* __restrict__ X, const float* __restrict__ G,
    const float* __restrict__ Bt, float* __restrict__ out) {
  __shared__ float w1[4], w2[4];
  int row = blockIdx.x, tid = threadIdx.x;
  const float4 v = ((const float4*)(X + (size_t)row * DM))[tid];
  float s = v.x + v.y + v.z + v.w;
  float s2 = v.x * v.x + v.y * v.y + v.z * v.z + v.w * v.w;
  #pragma unroll
  for (int m = 1; m < 64; m <<= 1) {
    s += __shfl_xor(s, m, 64);
    s2 += __shfl_xor(s2, m, 64);
  }
  int wid = tid >> 6;
  if ((tid & 63) == 0) { w1[wid] = s; w2[wid] = s2; }
  __syncthreads();
  float S = w1[0] + w1[1] + w1[2] + w1[3];
  float S2 = w2[0] + w2[1] + w2[2] + w2[3];
  float mu = S * (1.f / DM);
  float var = S2 * (1.f / DM) - mu * mu;
  float inv = 1.0f / sqrtf(var + 1e-3f);
  float4 g = ((const float4*)G)[tid];
  float4 b = ((const float4*)Bt)[tid];
  float4 o;
  o.x = (v.x - mu) * inv * g.x + b.x;
  o.y = (v.y - mu) * inv * g.y + b.y;
  o.z = (v.z - mu) * inv * g.z + b.z;
  o.w = (v.w - mu) * inv * g.w + b.w;
  ((float4*)(out + (size_t)row * DM))[tid] = o;
}

// ---------------------------------------------------------------------------
// Workspace: EXACTLY 200 MiB (proven). Phase-based aliasing:
//   [  0, 32) qk -> attnb | [32,64) v | [64,192) o_u (pre-attn: i_hi/i_lo/WR/
//   flags/flagc/buckets/Wqkvt/WR2t; post-comb: outp) |
//   [192,194) st [194,194.5) rn [196,198) slog_u [198,200) Wot
// ---------------------------------------------------------------------------
extern "C" void kernel_launch(void* const* d_in, const int* in_sizes, int n_in,
                              void* d_out, int out_size, void* d_ws, size_t ws_size,
                              hipStream_t stream) {
  const float* I   = (const float*)d_in[0];
  const float* R   = (const float*)d_in[2];
  const float* Wqk = (const float*)d_in[3];
  const float* Wv  = (const float*)d_in[4];
  const float* Wo  = (const float*)d_in[5];
  const float* bo  = (const float*)d_in[6];
  const float* lng = (const float*)d_in[7];
  const float* lnb = (const float*)d_in[8];

  char* ws = (char*)d_ws;
  const size_t MB = 1ull << 20;
  u16*      qk      = (u16*)(ws + 0);
  u16*      v       = (u16*)(ws + 32 * MB);
  u16*      o_u     = (u16*)(ws + 64 * MB);
  u16*      i_hi    = (u16*)(ws + 64 * MB);
  u16*      i_lo    = (u16*)(ws + 96 * MB);
  double*   WR      = (double*)(ws + 128 * MB);
  int*      flags   = (int*)(ws + 136 * MB);
  unsigned* flagc   = (unsigned*)(ws + 137 * MB);
  int*      buckets = (int*)(ws + 138 * MB);
  u16*      Wqkvt   = (u16*)(ws + 140 * MB);   // 4 MB [2048][1024]
  u16*      WR2t    = (u16*)(ws + 144 * MB);   // 4 MB
  float*    outp    = (float*)(ws + 64 * MB);
  int*      st      = (int*)(ws + 192 * MB);
  float*    rn      = (float*)(ws + 194 * MB); // 512 KB
  float*    slog_u  = (float*)(ws + 196 * MB);
  u16*      Wot     = (u16*)(ws + 198 * MB);
  u16*      attnb   = qk;
  float*    out     = (float*)d_out;

  k_isplit<<<8192, 256, 0, stream>>>(I, i_hi, i_lo);
  k_wr<<<dim3(16, 8), 256, 0, stream>>>(Wqk, R, WR);
  k_wsplit<<<512, 256, 0, stream>>>(Wqk, Wv, Wo, WR, Wqkvt, Wot, WR2t, flagc);
  // merged qk+v GEMM: N=2048, cols<1024 -> qk, cols>=1024 -> v
  k_gemm<0><<<dim3(128, 16), 256, 0, stream>>>(i_hi, nullptr, Wqkvt, qk, v, nullptr, nullptr, nullptr, nullptr, nullptr);
  k_norm<<<8192, 256, 0, stream>>>(qk, rn);
  k_gemm<2><<<dim3(128, 8), 256, 0, stream>>>(i_hi, i_lo, WR2t, nullptr, nullptr, nullptr, nullptr, buckets, flagc, flags);
  k_fb<<<1024, 64, 0, stream>>>(I, WR, flagc, flags, buckets);
  k_sort<<<dim3(BHN, NH), 64, 0, stream>>>(buckets, st);
  k_attn<<<dim3(BHN, NC), 256, 0, stream>>>(qk, v, st, rn, o_u, slog_u);
  k_comb<<<dim3(T_ / 16, BHN), 256, 0, stream>>>(o_u, slog_u, attnb);
  k_gemm<1><<<dim3(128, 8), 256, 0, stream>>>(attnb, nullptr, Wot, nullptr, nullptr, outp, bo, nullptr, nullptr, nullptr);
  k_ln<<<B_ * T_, 256, 0, stream>>>(outp, lng, lnb, out);
}

// Round 14
// 530.531 us; speedup vs baseline: 1.0258x; 1.0258x over previous
//
#include <hip/hip_runtime.h>
#include <hip/hip_bf16.h>

#define B_   4
#define T_   4096
#define DM   1024
#define H_   8
#define DH   128
#define BHN  32
#define NH   4
#define NB   64
#define NT   16384
#define NC   256
#define SCALE_ 0.08838834764831845f
#define SELF_VAL -50000.0f
#define FLAG_CAP 262144
#define GAP_THR 2.5e-3f

typedef unsigned short u16;
typedef __attribute__((ext_vector_type(8))) short short8;
typedef __attribute__((ext_vector_type(8))) unsigned short us8;
typedef __attribute__((ext_vector_type(4))) float f32x4;

__device__ __forceinline__ float bf2f(u16 x) {
  union { unsigned u; float f; } c; c.u = ((unsigned)x) << 16; return c.f;
}
__device__ __forceinline__ u16 f2bf(float f) {
  union { float f; unsigned u; } c; c.f = f;
  unsigned r = (c.u + 0x7FFFu + ((c.u >> 16) & 1u)) >> 16;
  return (u16)r;
}
// async global->LDS, 16B per lane; LDS dest = wave-uniform base + lane*16
__device__ __forceinline__ void gload16(const void* g, void* l) {
  __builtin_amdgcn_global_load_lds(
      (const __attribute__((address_space(1))) void*)g,
      (__attribute__((address_space(3))) void*)l, 16, 0, 0);
}

// ---------------------------------------------------------------------------
// P1: split i -> i_hi (bf16) and i_lo (bf16 of residual)
// ---------------------------------------------------------------------------
__global__ __launch_bounds__(256) void k_isplit(
    const float* __restrict__ I, u16* __restrict__ ih, u16* __restrict__ il) {
  size_t idx = ((size_t)blockIdx.x * 256 + threadIdx.x) * 8;
  us8 vh, vl;
  #pragma unroll
  for (int e = 0; e < 8; ++e) {
    float x = I[idx + e];
    u16 h = f2bf(x);
    vh[e] = h;
    vl[e] = f2bf(x - bf2f(h));
  }
  *(us8*)(ih + idx) = vh;
  *(us8*)(il + idx) = vl;
}

// ---------------------------------------------------------------------------
// P2: WR[h][k][hr] = sum_d Wqk[k][h*128+d] * R[d][hr]  (f64, for k_fb only)
// ---------------------------------------------------------------------------
__global__ __launch_bounds__(256) void k_wr(
    const float* __restrict__ Wqk, const float* __restrict__ R, double* __restrict__ WR) {
  __shared__ float lR[128][128];
  int tid = threadIdx.x;
  int k0 = blockIdx.x * 64, h = blockIdx.y;
  #pragma unroll
  for (int q = 0; q < 64; ++q)
    ((float*)lR)[q * 256 + tid] = R[q * 256 + tid];
  __syncthreads();
  int k = k0 + (tid >> 2);
  int hr0 = (tid & 3) * 32;
  double acc[32];
  #pragma unroll
  for (int j = 0; j < 32; ++j) acc[j] = 0.0;
  for (int d = 0; d < 128; ++d) {
    double w = (double)Wqk[(size_t)k * DM + h * DH + d];
    #pragma unroll
    for (int j = 0; j < 32; ++j)
      acc[j] = fma(w, (double)lR[d][hr0 + j], acc[j]);
  }
  double* o = WR + ((size_t)h * 1024 + k) * 128 + hr0;
  #pragma unroll
  for (int j = 0; j < 32; ++j) o[j] = acc[j];
}

// ---------------------------------------------------------------------------
// P3: transpose+split weights (also zeroes flagc): Wqkvt contiguous [2048][1024],
// Wot bf16 [n][k], WR2t [n][2048]={hi,lo}
// ---------------------------------------------------------------------------
__global__ __launch_bounds__(256) void k_wsplit(
    const float* __restrict__ Wqk, const float* __restrict__ Wv,
    const float* __restrict__ Wo, const double* __restrict__ WR,
    u16* __restrict__ Wqkvt, u16* __restrict__ Wot, u16* __restrict__ WR2t,
    unsigned* __restrict__ flagc) {
  if (blockIdx.x == 0 && threadIdx.x == 0) *flagc = 0;
  int tid = blockIdx.x * 256 + threadIdx.x;   // 131072
  int k = tid >> 7, n8 = (tid & 127) << 3;
  #pragma unroll
  for (int j = 0; j < 8; ++j) {
    int n = n8 + j;
    Wqkvt[(size_t)n * 1024 + k]          = f2bf(Wqk[(size_t)k * 1024 + n]);
    Wqkvt[(size_t)(1024 + n) * 1024 + k] = f2bf(Wv [(size_t)k * 1024 + n]);
    Wot  [(size_t)n * 1024 + k]          = f2bf(Wo [(size_t)k * 1024 + n]);
    double w = WR[((size_t)(n >> 7) * 1024 + k) * 128 + (n & 127)];
    u16 wh = f2bf((float)w);
    u16 wl = f2bf((float)(w - (double)bf2f(wh)));
    WR2t[(size_t)n * 2048 + k] = wh;
    WR2t[(size_t)n * 2048 + 1024 + k] = wl;
  }
}

// ---------------------------------------------------------------------------
// K-GEMM: C[M x N] = A * Bt^T, bf16 MFMA, 128x128 tile, gload_lds staging with
// 16B-chunk XOR swizzle (both-sides involution, rule #21).
// EPI 0: bf16 store, N=2048 split across outb (cols<1024) / outb2.
// EPI 1: f32 + bias (N=1024).
// EPI 2: rot GEMM as 3 segments [A*Bhi, A*Blo, A2*Bhi]; argmax epilogue.
// ---------------------------------------------------------------------------
template <int EPI>
__global__ __launch_bounds__(256) void k_gemm(
    const u16* __restrict__ A, const u16* __restrict__ A2,
    const u16* __restrict__ Bt,
    u16* __restrict__ outb, u16* __restrict__ outb2,
    float* __restrict__ outf, const float* __restrict__ bias,
    int* __restrict__ buckets, unsigned* __restrict__ flagc, int* __restrict__ flags) {
  __shared__ char smem[34816];                       // A[0,16K) B[16K,32K); sC 33792B
  u16 (*smA)[64] = (u16 (*)[64])smem;
  u16 (*smB)[64] = (u16 (*)[64])(smem + 16384);
  int tid = threadIdx.x;
  int m0 = blockIdx.x * 128, n0 = blockIdx.y * 128;
  int w = tid >> 6, lane = tid & 63;
  int wr = w >> 1, wc = w & 1;
  int arow = lane & 15, kg = lane >> 4;
  const int ldb = (EPI == 2) ? 2048 : 1024;
  int lrow = lane >> 3;                              // row within 8-row group = row&7
  int gch = (lane & 7) ^ lrow;                       // swizzled source 16B chunk

  f32x4 acc[4][4];
  #pragma unroll
  for (int m = 0; m < 4; ++m)
    #pragma unroll
    for (int n = 0; n < 4; ++n) acc[m][n] = (f32x4){0.f, 0.f, 0.f, 0.f};

  int axor = (arow & 7) << 3;                        // chunk-XOR premultiplied by 8

  auto run_seg = [&](const u16* Ab, const u16* Bb) {
    for (int kk = 0; kk < 1024; kk += 64) {
      __syncthreads();                               // prior MFMA reads done
      #pragma unroll
      for (int q = 0; q < 4; ++q) {
        int row = q * 32 + w * 8 + lrow;
        gload16(Ab + (size_t)(m0 + row) * 1024 + kk + gch * 8,
                smem + (q * 4096 + w * 1024));
        gload16(Bb + (size_t)(n0 + row) * ldb + kk + gch * 8,
                smem + 16384 + (q * 4096 + w * 1024));
      }
      __syncthreads();                               // staging drained
      #pragma unroll
      for (int ks = 0; ks < 2; ++ks) {
        short8 af[4], bf[4];
        #pragma unroll
        for (int m = 0; m < 4; ++m)
          af[m] = *(const short8*)(&smA[wr * 64 + m * 16 + arow][((ks * 4 + kg) << 3) ^ axor]);
        #pragma unroll
        for (int n = 0; n < 4; ++n)
          bf[n] = *(const short8*)(&smB[wc * 64 + n * 16 + arow][((ks * 4 + kg) << 3) ^ axor]);
        #pragma unroll
        for (int m = 0; m < 4; ++m)
          #pragma unroll
          for (int n = 0; n < 4; ++n)
            acc[m][n] = __builtin_amdgcn_mfma_f32_16x16x32_bf16(af[m], bf[n], acc[m][n], 0, 0, 0);
      }
    }
  };

  if constexpr (EPI == 2) {
    run_seg(A, Bt);            // i_hi * W_hi
    run_seg(A, Bt + 1024);     // i_hi * W_lo
    run_seg(A2, Bt);           // i_lo * W_hi
  } else {
    run_seg(A, Bt);
  }

  if constexpr (EPI == 0) {
    u16* dst = (n0 < 1024) ? outb : outb2;
    int nc0 = (n0 < 1024) ? n0 : (n0 - 1024);
    #pragma unroll
    for (int m = 0; m < 4; ++m)
      #pragma unroll
      for (int n = 0; n < 4; ++n)
        #pragma unroll
        for (int r = 0; r < 4; ++r) {
          int orow = wr * 64 + m * 16 + kg * 4 + r;
          int ocol = wc * 64 + n * 16 + arow;
          dst[(size_t)(m0 + orow) * 1024 + nc0 + ocol] = f2bf(acc[m][n][r]);
        }
  } else if constexpr (EPI == 1) {
    #pragma unroll
    for (int m = 0; m < 4; ++m)
      #pragma unroll
      for (int n = 0; n < 4; ++n)
        #pragma unroll
        for (int r = 0; r < 4; ++r) {
          int orow = wr * 64 + m * 16 + kg * 4 + r;
          int ocol = wc * 64 + n * 16 + arow;
          outf[(size_t)(m0 + orow) * 1024 + n0 + ocol] = acc[m][n][r] + bias[n0 + ocol];
        }
  } else {
    // rot epilogue: this block's N-tile is exactly head h = blockIdx.y.
    float (*sC)[132] = (float (*)[132])smem;         // 64*132*4 = 33792 B
    #pragma unroll
    for (int pass = 0; pass < 2; ++pass) {
      __syncthreads();   // previous phase done with smem
      if (wr == pass) {
        #pragma unroll
        for (int m = 0; m < 4; ++m)
          #pragma unroll
          for (int n = 0; n < 4; ++n)
            #pragma unroll
            for (int r = 0; r < 4; ++r)
              sC[m * 16 + kg * 4 + r][wc * 64 + n * 16 + arow] = acc[m][n][r];
      }
      __syncthreads();
      int tok = tid >> 2, hash = tid & 3;
      const float* rw = &sC[tok][hash * 32];
      float m1 = -3.4e38f, m2 = -3.4e38f; int bi = 0;
      #pragma unroll
      for (int j = 0; j < 32; ++j) {
        float vv = rw[j];
        if (vv > m1) { m2 = m1; m1 = vv; bi = j; }
        else if (vv > m2) m2 = vv;
      }
      #pragma unroll
      for (int j = 0; j < 32; ++j) {
        float vv = -rw[j];
        if (vv > m1) { m2 = m1; m1 = vv; bi = 32 + j; }
        else if (vv > m2) m2 = vv;
      }
      int bt = m0 + pass * 64 + tok;
      int b = bt >> 12, t = bt & 4095;
      buckets[((size_t)(b * 8 + blockIdx.y) * 4 + hash) * T_ + t] = bi;
      if (m1 - m2 < GAP_THR) {
        unsigned pos = atomicAdd(flagc, 1u);
        if (pos < FLAG_CAP) flags[pos] = (bt << 5) | ((int)blockIdx.y << 2) | hash;
      }
    }
  }
}

// ---------------------------------------------------------------------------
// f64 fallback for near-tie argmaxes: recompute 32 rot dots exactly.
// ---------------------------------------------------------------------------
__global__ __launch_bounds__(64) void k_fb(
    const float* __restrict__ I, const double* __restrict__ WR,
    const unsigned* __restrict__ flagc, const int* __restrict__ flags,
    int* __restrict__ buckets) {
  unsigned n = *flagc; if (n > FLAG_CAP) n = FLAG_CAP;
  int lane = threadIdx.x;
  for (unsigned it = blockIdx.x; it < n; it += gridDim.x) {
    int f = flags[it];
    int bt = f >> 5, h = (f >> 2) & 7, hash = f & 3;
    int j = lane & 31, half = lane >> 5;
    const float* ip = I + (size_t)bt * 1024 + half * 512;
    const double* wp = WR + ((size_t)h * 1024 + half * 512) * 128 + hash * 32 + j;
    double acc = 0.0;
    for (int k = 0; k < 512; ++k)
      acc = fma((double)ip[k], wp[(size_t)k * 128], acc);
    acc += __shfl_down(acc, 32, 64);
    double bv = acc; int bi = j;
    double vneg = -acc;
    if (vneg > bv) { bv = vneg; bi = 32 + j; }
    #pragma unroll
    for (int m = 1; m < 32; m <<= 1) {
      double ov = __shfl_xor(bv, m, 64);
      int oi = __shfl_xor(bi, m, 64);
      if (ov > bv || (ov == bv && oi < bi)) { bv = ov; bi = oi; }
    }
    if (lane == 0) {
      int b = bt >> 12, t = bt & 4095;
      buckets[((size_t)(b * 8 + h) * 4 + hash) * T_ + t] = bi;
    }
  }
}

// ---------------------------------------------------------------------------
// K3: stable counting sort (st only)
// ---------------------------------------------------------------------------
__global__ __launch_bounds__(64) void k_sort(
    const int* __restrict__ buckets, int* __restrict__ st) {
  __shared__ int hist[64][65];
  __shared__ int base[64];
  int bh = blockIdx.x, r = blockIdx.y;
  int m = threadIdx.x;
  #pragma unroll
  for (int b = 0; b < 64; ++b) hist[b][m] = 0;
  __syncthreads();
  const int* bk = buckets + ((size_t)bh * NH + r) * T_;
  for (int q = 0; q < 64; ++q) hist[bk[m * 64 + q]][m]++;
  __syncthreads();
  {
    int run = 0;
    for (int c = 0; c < 64; ++c) { int x = hist[m][c]; hist[m][c] = run; run += x; }
    base[m] = run;
  }
  __syncthreads();
  if (m == 0) {
    int s = 0;
    for (int b = 0; b < 64; ++b) { int x = base[b]; base[b] = s; s += x; }
  }
  __syncthreads();
  int* stb = st + (size_t)bh * NT + (size_t)r * T_;
  for (int q = 0; q < 64; ++q) {
    int t = m * 64 + q;
    int b = bk[t];
    int pos = base[b] + hist[b][m]++;
    stb[pos] = t;
  }
}

// ---------------------------------------------------------------------------
// k_attn (r11-proven version): bh-major grid; V^T in LDS; psum/recipn aliased
// into pbuf; setprio(1) around MFMA clusters; unsorted scatter-out.
// LDS rows are 128 data + 8 pad = 136 u16 (row width MUST be >= 128!).
// ---------------------------------------------------------------------------
__global__ __launch_bounds__(256) void k_attn(
    const u16* __restrict__ qk, const u16* __restrict__ V, const int* __restrict__ st,
    u16* __restrict__ o_u, float* __restrict__ slog_u) {
  __shared__ u16 kbuf[128][136];   // q rows [key][d]; later V^T [d][key]
  __shared__ u16 pbuf[64][136];    // probs bf16 [q][key]
  __shared__ int tks[128];
  float* psum   = (float*)&pbuf[0][0];
  float* recipn = (float*)&pbuf[4][0];
  int tid = threadIdx.x;
  int bh = blockIdx.x, chunk = blockIdx.y;
  int round = chunk >> 6;
  int bb_ = bh >> 3, hh_ = bh & 7;
  const int* stb = st + (size_t)bh * NT;
  if (tid < 128) {
    int j = tid;
    int p = (j < 64) ? (chunk * 64 + j)
                     : (((chunk + NC - 1) % NC) * 64 + (j - 64));
    tks[j] = stb[p];
  }
  __syncthreads();
  {
    int j = tid & 127, half = tid >> 7;
    const ushort4* rp = (const ushort4*)(qk + ((size_t)(bb_ * T_ + tks[j])) * DM + hh_ * DH + half * 64);
    ushort4* dp = (ushort4*)(&kbuf[j][half * 64]);
    float ss = 0.f;
    #pragma unroll
    for (int c = 0; c < 16; ++c) {
      ushort4 x = rp[c];
      float f0 = bf2f(x.x), f1 = bf2f(x.y), f2 = bf2f(x.z), f3 = bf2f(x.w);
      ss += f0 * f0 + f1 * f1 + f2 * f2 + f3 * f3;
      dp[c] = x;
    }
    psum[j * 2 + half] = ss;
  }
  __syncthreads();
  if (tid < 128) {
    float n = sqrtf(psum[tid * 2] + psum[tid * 2 + 1]);
    recipn[tid] = 1.f / fmaxf(n, 1e-6f);
  }
  __syncthreads();

  int w = tid >> 6, lane = tid & 63;
  int arow = lane & 15, kgrp = lane >> 4;

  f32x4 acc[8];
  #pragma unroll
  for (int n = 0; n < 8; ++n) acc[n] = (f32x4){0.f, 0.f, 0.f, 0.f};
  __builtin_amdgcn_s_setprio(1);
  #pragma unroll
  for (int kk = 0; kk < 4; ++kk) {
    short8 a = *(const short8*)(&kbuf[w * 16 + arow][kk * 32 + kgrp * 8]);
    #pragma unroll
    for (int n = 0; n < 8; ++n) {
      short8 bb = *(const short8*)(&kbuf[n * 16 + arow][kk * 32 + kgrp * 8]);
      acc[n] = __builtin_amdgcn_mfma_f32_16x16x32_bf16(a, bb, acc[n], 0, 0, 0);
    }
  }
  __builtin_amdgcn_s_setprio(0);

  int ti[4];
  #pragma unroll
  for (int r = 0; r < 4; ++r) ti[r] = tks[w * 16 + kgrp * 4 + r];
  float vals[8][4];
  float rmax[4] = {-3.0e38f, -3.0e38f, -3.0e38f, -3.0e38f};
  #pragma unroll
  for (int n = 0; n < 8; ++n) {
    int j = n * 16 + arow;
    float rc = recipn[j] * SCALE_;
    int tj = tks[j];
    #pragma unroll
    for (int r = 0; r < 4; ++r) {
      float d = acc[n][r] * rc;
      if (ti[r] == tj) d = SELF_VAL;
      vals[n][r] = d;
      rmax[r] = fmaxf(rmax[r], d);
    }
  }
  __syncthreads();   // recipn/psum fully read before pbuf writes
  #pragma unroll
  for (int m = 1; m <= 8; m <<= 1) {
    #pragma unroll
    for (int r = 0; r < 4; ++r) rmax[r] = fmaxf(rmax[r], __shfl_xor(rmax[r], m, 64));
  }
  float rsum[4] = {0.f, 0.f, 0.f, 0.f};
  #pragma unroll
  for (int n = 0; n < 8; ++n) {
    #pragma unroll
    for (int r = 0; r < 4; ++r) {
      float e = __expf(vals[n][r] - rmax[r]);
      vals[n][r] = e;
      rsum[r] += e;
    }
  }
  #pragma unroll
  for (int m = 1; m <= 8; m <<= 1) {
    #pragma unroll
    for (int r = 0; r < 4; ++r) rsum[r] += __shfl_xor(rsum[r], m, 64);
  }
  float rinv[4], lse[4];
  #pragma unroll
  for (int r = 0; r < 4; ++r) {
    rinv[r] = 1.f / rsum[r];
    lse[r] = rmax[r] + __logf(rsum[r]);
  }
  if (arow == 0) {
    #pragma unroll
    for (int r = 0; r < 4; ++r)
      slog_u[((size_t)(bh * NH + round)) * T_ + ti[r]] = lse[r];
  }
  #pragma unroll
  for (int n = 0; n < 8; ++n) {
    #pragma unroll
    for (int r = 0; r < 4; ++r)
      pbuf[w * 16 + kgrp * 4 + r][n * 16 + arow] = f2bf(vals[n][r] * rinv[r]);
  }
  __syncthreads();   // done reading kbuf (q) -> overwrite with V^T
  {
    int j = tid & 127, half = tid >> 7;
    const us8* rp = (const us8*)(V + ((size_t)(bb_ * T_ + tks[j])) * DM + hh_ * DH + half * 64);
    #pragma unroll
    for (int c = 0; c < 8; ++c) {
      us8 x = rp[c];
      int d = half * 64 + c * 8;
      #pragma unroll
      for (int e = 0; e < 8; ++e) kbuf[d + e][j] = (u16)x[e];
    }
  }
  __syncthreads();

  f32x4 acc2[8];
  #pragma unroll
  for (int n = 0; n < 8; ++n) acc2[n] = (f32x4){0.f, 0.f, 0.f, 0.f};
  __builtin_amdgcn_s_setprio(1);
  #pragma unroll
  for (int kk = 0; kk < 4; ++kk) {
    short8 a = *(const short8*)(&pbuf[w * 16 + arow][kk * 32 + kgrp * 8]);
    #pragma unroll
    for (int n = 0; n < 8; ++n) {
      short8 bb = *(const short8*)(&kbuf[n * 16 + arow][kk * 32 + kgrp * 8]);
      acc2[n] = __builtin_amdgcn_mfma_f32_16x16x32_bf16(a, bb, acc2[n], 0, 0, 0);
    }
  }
  __builtin_amdgcn_s_setprio(0);
  u16* ob = o_u + ((size_t)(bh * NH + round)) * T_ * DH;
  #pragma unroll
  for (int n = 0; n < 8; ++n) {
    #pragma unroll
    for (int r = 0; r < 4; ++r)
      ob[(size_t)ti[r] * DH + n * 16 + arow] = f2bf(acc2[n][r]);
  }
}

// ---------------------------------------------------------------------------
// k_comb: unsorted inputs -> fully coalesced. 16 tokens per block.
// ---------------------------------------------------------------------------
__global__ __launch_bounds__(256) void k_comb(
    const u16* __restrict__ o_u, const float* __restrict__ slog_u,
    u16* __restrict__ attn) {
  int tid = threadIdx.x;
  int bh = blockIdx.y;
  int t0 = blockIdx.x * 16;
  int dd = tid & 127;
  int b = bh >> 3, h = bh & 7;
  #pragma unroll
  for (int i = 0; i < 8; ++i) {
    int t = t0 + (tid >> 7) + i * 2;
    float l[4];
    #pragma unroll
    for (int r = 0; r < 4; ++r)
      l[r] = slog_u[((size_t)(bh * NH + r)) * T_ + t];
    float m = fmaxf(fmaxf(l[0], l[1]), fmaxf(l[2], l[3]));
    float wv[4]; float wsum = 0.f;
    #pragma unroll
    for (int r = 0; r < 4; ++r) { wv[r] = __expf(l[r] - m); wsum += wv[r]; }
    float rs = 1.f / wsum;
    float o = 0.f;
    #pragma unroll
    for (int r = 0; r < 4; ++r)
      o += wv[r] * bf2f(o_u[(((size_t)(bh * NH + r)) * T_ + t) * DH + dd]);
    o *= rs;
    attn[((size_t)(b * T_ + t)) * DM + h * DH + dd] = f2bf(o);
  }
}

__global__ __launch_bounds__(256) void k_ln(
    const float* __restrict__ X, const float* __restrict__ G,
    const float* __restrict__ Bt, float* __restrict__ out) {
  __shared__ float w1[4], w2[4];
  int row = blockIdx.x, tid = threadIdx.x;
  const float4 v = ((const float4*)(X + (size_t)row * DM))[tid];
  float s = v.x + v.y + v.z + v.w;
  float s2 = v.x * v.x + v.y * v.y + v.z * v.z + v.w * v.w;
  #pragma unroll
  for (int m = 1; m < 64; m <<= 1) {
    s += __shfl_xor(s, m, 64);
    s2 += __shfl_xor(s2, m, 64);
  }
  int wid = tid >> 6;
  if ((tid & 63) == 0) { w1[wid] = s; w2[wid] = s2; }
  __syncthreads();
  float S = w1[0] + w1[1] + w1[2] + w1[3];
  float S2 = w2[0] + w2[1] + w2[2] + w2[3];
  float mu = S * (1.f / DM);
  float var = S2 * (1.f / DM) - mu * mu;
  float inv = 1.0f / sqrtf(var + 1e-3f);
  float4 g = ((const float4*)G)[tid];
  float4 b = ((const float4*)Bt)[tid];
  float4 o;
  o.x = (v.x - mu) * inv * g.x + b.x;
  o.y = (v.y - mu) * inv * g.y + b.y;
  o.z = (v.z - mu) * inv * g.z + b.z;
  o.w = (v.w - mu) * inv * g.w + b.w;
  ((float4*)(out + (size_t)row * DM))[tid] = o;
}

// ---------------------------------------------------------------------------
// Workspace: EXACTLY 200 MiB (proven). Phase-based aliasing:
//   [  0, 32) qk -> attnb | [32,64) v | [64,192) o_u (pre-attn: i_hi/i_lo/WR/
//   flags/flagc/buckets/Wqkvt/WR2t; post-comb: outp) |
//   [192,194) st [196,198) slog_u [198,200) Wot
// ---------------------------------------------------------------------------
extern "C" void kernel_launch(void* const* d_in, const int* in_sizes, int n_in,
                              void* d_out, int out_size, void* d_ws, size_t ws_size,
                              hipStream_t stream) {
  const float* I   = (const float*)d_in[0];
  const float* R   = (const float*)d_in[2];
  const float* Wqk = (const float*)d_in[3];
  const float* Wv  = (const float*)d_in[4];
  const float* Wo  = (const float*)d_in[5];
  const float* bo  = (const float*)d_in[6];
  const float* lng = (const float*)d_in[7];
  const float* lnb = (const float*)d_in[8];

  char* ws = (char*)d_ws;
  const size_t MB = 1ull << 20;
  u16*      qk      = (u16*)(ws + 0);
  u16*      v       = (u16*)(ws + 32 * MB);
  u16*      o_u     = (u16*)(ws + 64 * MB);
  u16*      i_hi    = (u16*)(ws + 64 * MB);
  u16*      i_lo    = (u16*)(ws + 96 * MB);
  double*   WR      = (double*)(ws + 128 * MB);
  int*      flags   = (int*)(ws + 136 * MB);
  unsigned* flagc   = (unsigned*)(ws + 137 * MB);
  int*      buckets = (int*)(ws + 138 * MB);
  u16*      Wqkvt   = (u16*)(ws + 140 * MB);   // 4 MB [2048][1024]
  u16*      WR2t    = (u16*)(ws + 144 * MB);   // 4 MB
  float*    outp    = (float*)(ws + 64 * MB);
  int*      st      = (int*)(ws + 192 * MB);
  float*    slog_u  = (float*)(ws + 196 * MB);
  u16*      Wot     = (u16*)(ws + 198 * MB);
  u16*      attnb   = qk;
  float*    out     = (float*)d_out;

  k_isplit<<<8192, 256, 0, stream>>>(I, i_hi, i_lo);
  k_wr<<<dim3(16, 8), 256, 0, stream>>>(Wqk, R, WR);
  k_wsplit<<<512, 256, 0, stream>>>(Wqk, Wv, Wo, WR, Wqkvt, Wot, WR2t, flagc);
  // merged qk+v GEMM: N=2048, cols<1024 -> qk, cols>=1024 -> v
  k_gemm<0><<<dim3(128, 16), 256, 0, stream>>>(i_hi, nullptr, Wqkvt, qk, v, nullptr, nullptr, nullptr, nullptr, nullptr);
  k_gemm<2><<<dim3(128, 8), 256, 0, stream>>>(i_hi, i_lo, WR2t, nullptr, nullptr, nullptr, nullptr, buckets, flagc, flags);
  k_fb<<<1024, 64, 0, stream>>>(I, WR, flagc, flags, buckets);
  k_sort<<<dim3(BHN, NH), 64, 0, stream>>>(buckets, st);
  k_attn<<<dim3(BHN, NC), 256, 0, stream>>>(qk, v, st, o_u, slog_u);
  k_comb<<<dim3(T_ / 16, BHN), 256, 0, stream>>>(o_u, slog_u, attnb);
  k_gemm<1><<<dim3(128, 8), 256, 0, stream>>>(attnb, nullptr, Wot, nullptr, nullptr, outp, bo, nullptr, nullptr, nullptr);
  k_ln<<<B_ * T_, 256, 0, stream>>>(outp, lng, lnb, out);
}